// Round 1
// baseline (1151.299 us; speedup 1.0000x reference)
//
#include <hip/hip_runtime.h>
#include <math.h>

// Problem constants (B=4, T=48, W=8, H=8, C=32; d_ff=64; periods 2,3,4)
#define NB 4
#define NT 48
#define NWH 64                 // W*H
#define C1 32
#define C2 64
#define NPOS (NB*NT*NWH)       // 12288 positions
#define H1_PER (NPOS*C2)       // 786432 floats per period
#define H2_PER (NPOS*C1)       // 393216 floats per period
#define WE1 (81*C1*C2)         // 165888 effective layer-1 weights
#define WE2 (81*C2*C1)         // 165888 effective layer-2 weights

__device__ __forceinline__ float gelu_exact(float v) {
    return 0.5f * v * (1.0f + erff(v * 0.7071067811865476f));
}

// Build effective weights with the 1x1 conv folded into the 3^4 conv's center
// tap (tap 40) and the inception /2 pre-applied.
// w1e layout: [tap][c(32)][o(64)]   w2e layout: [tap][c(64)][o(32)]
__global__ void prep_weights(const float* __restrict__ w1_0,
                             const float* __restrict__ w1_1,
                             const float* __restrict__ w2_0,
                             const float* __restrict__ w2_1,
                             float* __restrict__ w1e,
                             float* __restrict__ w2e) {
    int i = blockIdx.x * blockDim.x + threadIdx.x;
    if (i < WE1) {
        int tap = i / (C1 * C2);
        int rem = i - tap * (C1 * C2);
        int c = rem >> 6;          // /64
        int o = rem & 63;
        float v = 0.5f * w1_1[(o * C1 + c) * 81 + tap];
        if (tap == 40) v += 0.5f * w1_0[o * C1 + c];
        w1e[i] = v;
    } else if (i < WE1 + WE2) {
        int j = i - WE1;
        int tap = j / (C2 * C1);
        int rem = j - tap * (C2 * C1);
        int c = rem >> 5;          // /32
        int o = rem & 31;
        float v = 0.5f * w2_1[(o * C2 + c) * 81 + tap];
        if (tap == 40) v += 0.5f * w2_0[o * C2 + c];
        w2e[j] = v;
    }
}

// Layer 1: 81-tap 4D conv (C1->C2) + exact GELU, all 3 periods in one grid.
// Block = 64 threads = one wave = one full (w,h) plane at uniform (b,t).
// Each thread computes 32 of the 64 output channels (half uniform per block).
// grid.x = 3 periods * 2 halves * 192 (b,t) = 1152
__global__ __launch_bounds__(64) void conv1_gelu(
    const float* __restrict__ x, const float* __restrict__ w1e,
    float* __restrict__ h1) {
    int per = blockIdx.x / 384;
    int blk = blockIdx.x - per * 384;
    int half = blk / 192;          // uniform: which 32-wide output-channel half
    int bt = blk - half * 192;     // uniform: b*48 + t
    int b = bt / NT;
    int t = bt - b * NT;
    int P = per + 2;               // periods are 2,3,4
    int L = NT / P;
    int l = t / P;
    int q = t - l * P;
    int wh = threadIdx.x;          // per-lane
    int w = wh >> 3, h = wh & 7;

    float acc[32];
#pragma unroll
    for (int o = 0; o < 32; ++o) acc[o] = 0.f;

    const float* wb = w1e + half * 32;

#pragma unroll 1
    for (int dl = 0; dl < 3; ++dl) {
        int l2 = l + dl - 1;
        if ((unsigned)l2 >= (unsigned)L) continue;   // uniform branch
#pragma unroll 1
        for (int dq = 0; dq < 3; ++dq) {
            int q2 = q + dq - 1;
            if ((unsigned)q2 >= (unsigned)P) continue; // uniform branch
            int t2 = l2 * P + q2;                      // uniform
            const float* xrow = x + (size_t)(b * NT + t2) * NWH * C1;
            int tapbase = (dl * 3 + dq) * 9;
#pragma unroll 1
            for (int dw = 0; dw < 3; ++dw) {
                int w2 = w + dw - 1;
                bool vw = (unsigned)w2 < 8u;
                int w2c = vw ? w2 : w;
#pragma unroll 1
                for (int dh = 0; dh < 3; ++dh) {
                    int h2 = h + dh - 1;
                    bool vh = (unsigned)h2 < 8u;
                    int h2c = vh ? h2 : h;
                    bool valid = vw && vh;             // per-lane
                    int tap = tapbase + dw * 3 + dh;
                    const float* xp = xrow + (w2c * 8 + h2c) * C1;
                    const float* wp = wb + tap * (C1 * C2);
#pragma unroll
                    for (int c = 0; c < C1; c += 4) {
                        float4 xv = *(const float4*)(xp + c);
                        if (!valid) { xv.x = 0.f; xv.y = 0.f; xv.z = 0.f; xv.w = 0.f; }
#pragma unroll
                        for (int cc = 0; cc < 4; ++cc) {
                            float xs = (cc == 0) ? xv.x : (cc == 1) ? xv.y
                                     : (cc == 2) ? xv.z : xv.w;
                            const float* wr = wp + (c + cc) * C2;  // uniform addr
#pragma unroll
                            for (int o = 0; o < 32; ++o)
                                acc[o] = fmaf(wr[o], xs, acc[o]);
                        }
                    }
                }
            }
        }
    }

    float* hp = h1 + (size_t)per * H1_PER + (size_t)(bt * NWH + wh) * C2 + half * 32;
#pragma unroll
    for (int o = 0; o < 32; o += 4) {
        float4 v;
        v.x = gelu_exact(acc[o + 0]);
        v.y = gelu_exact(acc[o + 1]);
        v.z = gelu_exact(acc[o + 2]);
        v.w = gelu_exact(acc[o + 3]);
        *(float4*)(hp + o) = v;
    }
}

// Layer 2: 81-tap 4D conv (C2->C1), writes per-period h2.
// grid.x = 3 periods * 192 (b,t) = 576, block = 64
__global__ __launch_bounds__(64) void conv2_kern(
    const float* __restrict__ h1, const float* __restrict__ w2e,
    float* __restrict__ h2) {
    int per = blockIdx.x / 192;
    int bt = blockIdx.x - per * 192;
    int b = bt / NT;
    int t = bt - b * NT;
    int P = per + 2;
    int L = NT / P;
    int l = t / P;
    int q = t - l * P;
    int wh = threadIdx.x;
    int w = wh >> 3, h = wh & 7;

    float acc[32];
#pragma unroll
    for (int o = 0; o < 32; ++o) acc[o] = 0.f;

    const float* hbase = h1 + (size_t)per * H1_PER;

#pragma unroll 1
    for (int dl = 0; dl < 3; ++dl) {
        int l2 = l + dl - 1;
        if ((unsigned)l2 >= (unsigned)L) continue;
#pragma unroll 1
        for (int dq = 0; dq < 3; ++dq) {
            int q2 = q + dq - 1;
            if ((unsigned)q2 >= (unsigned)P) continue;
            int t2 = l2 * P + q2;
            const float* hrow = hbase + (size_t)(b * NT + t2) * NWH * C2;
            int tapbase = (dl * 3 + dq) * 9;
#pragma unroll 1
            for (int dw = 0; dw < 3; ++dw) {
                int w2 = w + dw - 1;
                bool vw = (unsigned)w2 < 8u;
                int w2c = vw ? w2 : w;
#pragma unroll 1
                for (int dh = 0; dh < 3; ++dh) {
                    int h2i = h + dh - 1;
                    bool vh = (unsigned)h2i < 8u;
                    int h2c = vh ? h2i : h;
                    bool valid = vw && vh;
                    int tap = tapbase + dw * 3 + dh;
                    const float* xp = hrow + (w2c * 8 + h2c) * C2;
                    const float* wp = w2e + tap * (C2 * C1);
#pragma unroll
                    for (int c = 0; c < C2; c += 4) {
                        float4 xv = *(const float4*)(xp + c);
                        if (!valid) { xv.x = 0.f; xv.y = 0.f; xv.z = 0.f; xv.w = 0.f; }
#pragma unroll
                        for (int cc = 0; cc < 4; ++cc) {
                            float xs = (cc == 0) ? xv.x : (cc == 1) ? xv.y
                                     : (cc == 2) ? xv.z : xv.w;
                            const float* wr = wp + (c + cc) * C1;  // uniform addr
#pragma unroll
                            for (int o = 0; o < 32; ++o)
                                acc[o] = fmaf(wr[o], xs, acc[o]);
                        }
                    }
                }
            }
        }
    }

    float* op = h2 + (size_t)per * H2_PER + (size_t)(bt * NWH + wh) * C1;
#pragma unroll
    for (int o = 0; o < 32; o += 4) {
        float4 v;
        v.x = acc[o + 0];
        v.y = acc[o + 1];
        v.z = acc[o + 2];
        v.w = acc[o + 3];
        *(float4*)(op + o) = v;
    }
}

// out = x + (h2_p0 + h2_p1 + h2_p2) / 3   (softmax of ones = 1/3 each)
__global__ void final_add(const float* __restrict__ x,
                          const float* __restrict__ h2,
                          float* __restrict__ out) {
    int i = blockIdx.x * blockDim.x + threadIdx.x;  // float4 index
    float4 xv = ((const float4*)x)[i];
    float4 a = ((const float4*)h2)[i];
    float4 bv = ((const float4*)(h2 + H2_PER))[i];
    float4 cv = ((const float4*)(h2 + 2 * H2_PER))[i];
    const float s = 1.0f / 3.0f;
    float4 o;
    o.x = xv.x + (a.x + bv.x + cv.x) * s;
    o.y = xv.y + (a.y + bv.y + cv.y) * s;
    o.z = xv.z + (a.z + bv.z + cv.z) * s;
    o.w = xv.w + (a.w + bv.w + cv.w) * s;
    ((float4*)out)[i] = o;
}

extern "C" void kernel_launch(void* const* d_in, const int* in_sizes, int n_in,
                              void* d_out, int out_size, void* d_ws, size_t ws_size,
                              hipStream_t stream) {
    const float* x    = (const float*)d_in[0];
    const float* w1_0 = (const float*)d_in[1];
    const float* w1_1 = (const float*)d_in[2];
    const float* w2_0 = (const float*)d_in[3];
    const float* w2_1 = (const float*)d_in[4];
    float* out = (float*)d_out;

    // Workspace layout (floats): w1e | w2e | h1[3 periods] | h2[3 periods]
    float* w1e = (float*)d_ws;
    float* w2e = w1e + WE1;
    float* h1  = w2e + WE2;
    float* h2  = h1 + 3 * (size_t)H1_PER;
    // total: 2*165888 + 3*786432 + 3*393216 floats ~= 15.5 MB

    prep_weights<<<(WE1 + WE2 + 255) / 256, 256, 0, stream>>>(
        w1_0, w1_1, w2_0, w2_1, w1e, w2e);
    conv1_gelu<<<1152, 64, 0, stream>>>(x, w1e, h1);
    conv2_kern<<<576, 64, 0, stream>>>(h1, w2e, h2);
    final_add<<<H2_PER / 4 / 256, 256, 0, stream>>>(x, h2, out);
}

// Round 2
// 279.874 us; speedup vs baseline: 4.1136x; 4.1136x over previous
//
#include <hip/hip_runtime.h>
#include <math.h>

// Problem constants: B=4, T=48, W=8, H=8, C=32; d_ff=64; periods 2,3,4.
// T divisible by all periods -> no pad/concat path. softmax(ones)=1/3.
// (conv1x1 + conv3333)/2 folded into one 81-tap conv (center tap 40).

#define XPAD_ELEMS (4*48*100*32)       // 614400  bf16: x zero-padded in W,H to 10x10
#define W1B_ELEMS  (81*64*32)          // 165888  bf16: [tap][o=64][c=32]
#define W2B_ELEMS  (81*32*64)          // 165888  bf16: [tap][o=32][c=64]
#define H1PAD_PER  (4*48*100*64)       // 1228800 bf16 per period: [bt][10][10][64]
#define H1PAD_ELEMS (3*H1PAD_PER)
#define H2_PER     (4*48*64*32)        // 393216 fp32 per period: [bt][pos][c]

typedef __attribute__((ext_vector_type(8))) short bf16x8;   // 8 bf16 = 4 VGPRs
typedef __attribute__((ext_vector_type(4))) float f32x4;

__device__ __forceinline__ unsigned short f2bf(float f) {
    unsigned u = __float_as_uint(f);
    unsigned r = u + 0x7fffu + ((u >> 16) & 1u);   // RNE
    return (unsigned short)(r >> 16);
}

__device__ __forceinline__ float gelu_exact(float v) {
    return 0.5f * v * (1.0f + erff(v * 0.7071067811865476f));
}

// ---- prep: bf16-convert + pad x; build effective bf16 weights ----
__global__ __launch_bounds__(256) void prep(
    const float* __restrict__ x,
    const float* __restrict__ w1_0, const float* __restrict__ w1_1,
    const float* __restrict__ w2_0, const float* __restrict__ w2_1,
    unsigned short* __restrict__ xpad,
    unsigned short* __restrict__ w1b,
    unsigned short* __restrict__ w2b) {
    int i = blockIdx.x * 256 + threadIdx.x;
    if (i < XPAD_ELEMS) {
        int c = i & 31; int j = i >> 5;
        int hp = j % 10; j /= 10;
        int wp = j % 10; int bt = j / 10;
        float v = 0.f;
        if (hp >= 1 && hp < 9 && wp >= 1 && wp < 9)
            v = x[((bt * 8 + (wp - 1)) * 8 + (hp - 1)) * 32 + c];
        xpad[i] = f2bf(v);
    } else if (i < XPAD_ELEMS + W1B_ELEMS) {
        int j = i - XPAD_ELEMS;
        int c = j & 31; int k = j >> 5;
        int o = k & 63; int tap = k >> 6;
        float v = 0.5f * w1_1[(o * 32 + c) * 81 + tap];
        if (tap == 40) v += 0.5f * w1_0[o * 32 + c];
        w1b[j] = f2bf(v);
    } else if (i < XPAD_ELEMS + W1B_ELEMS + W2B_ELEMS) {
        int j = i - XPAD_ELEMS - W1B_ELEMS;
        int c = j & 63; int k = j >> 6;
        int o = k & 31; int tap = k >> 5;
        float v = 0.5f * w2_1[(o * 64 + c) * 81 + tap];
        if (tap == 40) v += 0.5f * w2_0[o * 64 + c];
        w2b[j] = f2bf(v);
    }
}

// ---- conv1 (C32->C64) + GELU, MFMA 16x16x32 bf16 ----
// grid = 3 periods * 192 bt; block = 256 (4 waves). Wave w: out channels
// [16w,16w+16); M = 64 positions (8x8 plane) = 4 M-tiles of 16.
__global__ __launch_bounds__(256) void conv1_mfma(
    const unsigned short* __restrict__ xpad,
    const unsigned short* __restrict__ w1b,
    unsigned short* __restrict__ h1pad) {
    int blk = blockIdx.x;
    int per = blk / 192; int bt = blk - per * 192;
    int t = bt % 48;
    int P = per + 2; int L = 48 / P;
    int l = t / P; int q = t - l * P;
    int lane = threadIdx.x & 63; int wave = threadIdx.x >> 6;
    int m = lane & 15, quad = lane >> 4;

    f32x4 acc[4];
#pragma unroll
    for (int mt = 0; mt < 4; ++mt) acc[mt] = f32x4{0.f, 0.f, 0.f, 0.f};

    int aoff[4];
#pragma unroll
    for (int mt = 0; mt < 4; ++mt) {
        int pos = mt * 16 + m;
        int w = pos >> 3, h = pos & 7;
        aoff[mt] = ((w + 1) * 10 + (h + 1)) * 32 + quad * 8;   // interior offset
    }
    const unsigned short* wb = w1b + (wave * 16 + m) * 32 + quad * 8;
    const unsigned short* xbt = xpad + bt * 3200;

    for (int dl = 0; dl < 3; ++dl) {
        int l2 = l + dl - 1;
        if (l2 < 0 || l2 >= L) continue;                 // uniform; pad-zero in L
        for (int dq = 0; dq < 3; ++dq) {
            int q2 = q + dq - 1;
            if (q2 < 0 || q2 >= P) continue;             // uniform; pad-zero in P
            int dt = (dl - 1) * P + (dq - 1);            // t2 = t + dt
            const unsigned short* xrow = xbt + dt * 3200;
            int tap0 = (dl * 3 + dq) * 9;
#pragma unroll
            for (int dwh = 0; dwh < 9; ++dwh) {
                int delta = (dwh / 3 - 1) * 320 + (dwh % 3 - 1) * 32;
                bf16x8 bfrag = *(const bf16x8*)(wb + (tap0 + dwh) * 2048);
#pragma unroll
                for (int mt = 0; mt < 4; ++mt) {
                    bf16x8 afrag = *(const bf16x8*)(xrow + aoff[mt] + delta);
                    acc[mt] = __builtin_amdgcn_mfma_f32_16x16x32_bf16(
                        afrag, bfrag, acc[mt], 0, 0, 0);
                }
            }
        }
    }

    // epilogue: GELU -> bf16 -> h1pad interior. D: row=quad*4+r, col=lane&15.
    unsigned short* hrow = h1pad + per * H1PAD_PER + bt * 6400;
    int o = wave * 16 + m;
#pragma unroll
    for (int mt = 0; mt < 4; ++mt) {
#pragma unroll
        for (int r = 0; r < 4; ++r) {
            int pos = mt * 16 + quad * 4 + r;
            int w = pos >> 3, h = pos & 7;
            hrow[((w + 1) * 10 + (h + 1)) * 64 + o] = f2bf(gelu_exact(acc[mt][r]));
        }
    }
}

// ---- conv2 (C64->C32), MFMA 16x16x32 bf16 ----
// grid = 3*192; block = 256 (4 waves). Wave = one M-tile (16 positions),
// N = 32 (2 N-tiles), K = 64 per tap (2 K-steps).
__global__ __launch_bounds__(256) void conv2_mfma(
    const unsigned short* __restrict__ h1pad,
    const unsigned short* __restrict__ w2b,
    float* __restrict__ h2) {
    int blk = blockIdx.x;
    int per = blk / 192; int bt = blk - per * 192;
    int t = bt % 48;
    int P = per + 2; int L = 48 / P;
    int l = t / P; int q = t - l * P;
    int lane = threadIdx.x & 63; int wave = threadIdx.x >> 6;
    int m = lane & 15, quad = lane >> 4;

    f32x4 acc[2];
    acc[0] = f32x4{0.f, 0.f, 0.f, 0.f};
    acc[1] = f32x4{0.f, 0.f, 0.f, 0.f};

    int pos = wave * 16 + m;
    int w = pos >> 3, h = pos & 7;
    int aoffbase = ((w + 1) * 10 + (h + 1)) * 64 + quad * 8;
    const unsigned short* hb = h1pad + per * H1PAD_PER + bt * 6400;
    const unsigned short* wb2 = w2b + m * 64 + quad * 8;

    for (int dl = 0; dl < 3; ++dl) {
        int l2 = l + dl - 1;
        if (l2 < 0 || l2 >= L) continue;
        for (int dq = 0; dq < 3; ++dq) {
            int q2 = q + dq - 1;
            if (q2 < 0 || q2 >= P) continue;
            int dt = (dl - 1) * P + (dq - 1);
            const unsigned short* hrow = hb + dt * 6400;
            int tap0 = (dl * 3 + dq) * 9;
#pragma unroll
            for (int dwh = 0; dwh < 9; ++dwh) {
                int delta = (dwh / 3 - 1) * 640 + (dwh % 3 - 1) * 64;
                const unsigned short* ap = hrow + aoffbase + delta;
                const unsigned short* wp = wb2 + (tap0 + dwh) * 2048;
#pragma unroll
                for (int ks = 0; ks < 2; ++ks) {
                    bf16x8 afrag = *(const bf16x8*)(ap + ks * 32);
#pragma unroll
                    for (int nt = 0; nt < 2; ++nt) {
                        bf16x8 bfrag = *(const bf16x8*)(wp + nt * 1024 + ks * 32);
                        acc[nt] = __builtin_amdgcn_mfma_f32_16x16x32_bf16(
                            afrag, bfrag, acc[nt], 0, 0, 0);
                    }
                }
            }
        }
    }

    // epilogue: fp32 -> h2[per][bt][pos][c]
    float* orow = h2 + per * H2_PER + bt * 2048;
#pragma unroll
    for (int nt = 0; nt < 2; ++nt) {
        int o = nt * 16 + m;
#pragma unroll
        for (int r = 0; r < 4; ++r) {
            int p2 = wave * 16 + quad * 4 + r;
            orow[p2 * 32 + o] = acc[nt][r];
        }
    }
}

// ---- out = x + (h2_p0 + h2_p1 + h2_p2) / 3 ----
__global__ __launch_bounds__(256) void final_add(
    const float* __restrict__ x, const float* __restrict__ h2,
    float* __restrict__ out) {
    int i = blockIdx.x * 256 + threadIdx.x;   // float4 index
    float4 xv = ((const float4*)x)[i];
    float4 a = ((const float4*)h2)[i];
    float4 bv = ((const float4*)(h2 + H2_PER))[i];
    float4 cv = ((const float4*)(h2 + 2 * H2_PER))[i];
    const float s = 1.0f / 3.0f;
    float4 o;
    o.x = xv.x + (a.x + bv.x + cv.x) * s;
    o.y = xv.y + (a.y + bv.y + cv.y) * s;
    o.z = xv.z + (a.z + bv.z + cv.z) * s;
    o.w = xv.w + (a.w + bv.w + cv.w) * s;
    ((float4*)out)[i] = o;
}

extern "C" void kernel_launch(void* const* d_in, const int* in_sizes, int n_in,
                              void* d_out, int out_size, void* d_ws, size_t ws_size,
                              hipStream_t stream) {
    const float* x    = (const float*)d_in[0];
    const float* w1_0 = (const float*)d_in[1];
    const float* w1_1 = (const float*)d_in[2];
    const float* w2_0 = (const float*)d_in[3];
    const float* w2_1 = (const float*)d_in[4];
    float* out = (float*)d_out;

    // Workspace layout: xpad | w1b | w2b | h1pad (all bf16) | h2 (fp32) ~14 MB
    unsigned short* xpad  = (unsigned short*)d_ws;
    unsigned short* w1b   = xpad + XPAD_ELEMS;
    unsigned short* w2b   = w1b + W1B_ELEMS;
    unsigned short* h1pad = w2b + W2B_ELEMS;
    float* h2 = (float*)(h1pad + H1PAD_ELEMS);

    // h1pad borders must be zero; conv1 writes interior only.
    hipMemsetAsync(h1pad, 0, (size_t)H1PAD_ELEMS * 2, stream);
    prep<<<(XPAD_ELEMS + W1B_ELEMS + W2B_ELEMS) / 256, 256, 0, stream>>>(
        x, w1_0, w1_1, w2_0, w2_1, xpad, w1b, w2b);
    conv1_mfma<<<576, 256, 0, stream>>>(xpad, w1b, h1pad);
    conv2_mfma<<<576, 256, 0, stream>>>(h1pad, w2b, h2);
    final_add<<<H2_PER / 4 / 256, 256, 0, stream>>>(x, h2, out);
}

// Round 3
// 220.589 us; speedup vs baseline: 5.2192x; 1.2688x over previous
//
#include <hip/hip_runtime.h>
#include <math.h>

// B=4, T=48, W=8, H=8, C=32; d_ff=64; periods {2,3,4}. T%P==0 always.
// (1x1 + 3^4)/2 inception folded into one 81-tap conv (center tap 40).
// All tensors padded in L,P,W,H so the 81-tap loop is branch-free.

typedef __attribute__((ext_vector_type(8))) short bf16x8;
typedef __attribute__((ext_vector_type(4))) float f32x4;
typedef unsigned short u16;

// ---- workspace element offsets (in u16 units unless noted) ----
// xpad3 per-period bases/sizes (C=32): per b: (L+2)*(P+2)*100*32
#define XB0 0
#define XB1 1331200            // 4 * 26*4*3200
#define XB2 2483200            // XB1 + 4 * 18*5*3200
#define XTOT 3558400           // XB2 + 4 * 14*6*3200
#define W1OFF XTOT             // 165888 bf16  [tap][o=64][c=32]
#define W2OFF (XTOT + 165888)  // 165888 bf16  [tap][o=32][c=64]
#define H1OFF (XTOT + 331776)  // h1pad3 (C=64)
#define HB0 0
#define HB1 2662400            // 4 * 26*4*6400
#define HB2 4966400            // HB1 + 4 * 18*5*6400
#define H1TOT 7116800          // HB2 + 4 * 14*6*6400
#define H2OFF_U16 (H1OFF + H1TOT)   // fp32 region starts here (u16 offset, even)
#define H2_PER 393216          // fp32 elems per period: 192*64*32
#define PREP_N (XTOT + 331776) // 3890176 = 15196 * 256

__device__ __forceinline__ u16 f2bf(float f) {
    unsigned u = __float_as_uint(f);
    unsigned r = u + 0x7fffu + ((u >> 16) & 1u);
    return (u16)(r >> 16);
}
__device__ __forceinline__ float gelu_exact(float v) {
    return 0.5f * v * (1.0f + erff(v * 0.7071067811865476f));
}

// ---- prep: padded bf16 x (3 period layouts) + effective bf16 weights ----
__global__ __launch_bounds__(256) void prep(
    const float* __restrict__ x,
    const float* __restrict__ w1_0, const float* __restrict__ w1_1,
    const float* __restrict__ w2_0, const float* __restrict__ w2_1,
    u16* __restrict__ ws) {
    int i = blockIdx.x * 256 + threadIdx.x;
    if (i < XTOT) {
        int j, P, L;
        if (i < XB1)      { j = i;       P = 2; L = 24; }
        else if (i < XB2) { j = i - XB1; P = 3; L = 16; }
        else              { j = i - XB2; P = 4; L = 12; }
        int SZ = (L + 2) * (P + 2) * 3200;
        int b = j / SZ; int r = j - b * SZ;
        int c = r & 31; int s = r >> 5;
        int hp = s % 10; s /= 10;
        int wp = s % 10; s /= 10;
        int qp = s % (P + 2); int lp = s / (P + 2);
        float v = 0.f;
        if (lp >= 1 && lp <= L && qp >= 1 && qp <= P &&
            wp >= 1 && wp <= 8 && hp >= 1 && hp <= 8) {
            int t = (lp - 1) * P + (qp - 1);
            v = x[((b * 48 + t) * 64 + (wp - 1) * 8 + (hp - 1)) * 32 + c];
        }
        ws[i] = f2bf(v);
    } else if (i < W2OFF) {
        int j = i - W1OFF;
        int c = j & 31; int k = j >> 5;
        int o = k & 63; int tap = k >> 6;
        float v = 0.5f * w1_1[(o * 32 + c) * 81 + tap];
        if (tap == 40) v += 0.5f * w1_0[o * 32 + c];
        ws[i] = f2bf(v);
    } else if (i < PREP_N) {
        int j = i - W2OFF;
        int c = j & 63; int k = j >> 6;
        int o = k & 31; int tap = k >> 5;
        float v = 0.5f * w2_1[(o * 64 + c) * 81 + tap];
        if (tap == 40) v += 0.5f * w2_0[o * 64 + c];
        ws[i] = f2bf(v);
    }
}

// ---- conv1 (C32->C64) + GELU. Wave = one t, 32 out-ch half.
// acc[4 Mt][2 Nt]; 81 branch-free taps, constexpr strides. ----
template<int P>
__device__ __forceinline__ void conv1_body(
    const u16* __restrict__ xpad, const u16* __restrict__ w1b,
    u16* __restrict__ h1pad, int half, int bt) {
    constexpr int L = 48 / P;
    constexpr int XB = (P == 2) ? XB0 : (P == 3) ? XB1 : XB2;
    constexpr int HB = (P == 2) ? HB0 : (P == 3) ? HB1 : HB2;
    constexpr int XSTR = (L + 2) * (P + 2) * 3200;
    constexpr int HSTR = (L + 2) * (P + 2) * 6400;

    int lane = threadIdx.x;
    int m = lane & 15, quad = lane >> 4;
    int b = bt / 48, t = bt - b * 48;
    int l = t / P, q = t - l * P;

    const u16* xb = xpad + XB + b * XSTR + (l * (P + 2) + q) * 3200;
    const u16* wb = w1b + (half * 32 + m) * 32 + quad * 8;

    int sp[4];
#pragma unroll
    for (int mt = 0; mt < 4; ++mt) {
        int pos = mt * 16 + m;
        sp[mt] = ((pos >> 3) * 10 + (pos & 7)) * 32 + quad * 8;
    }

    f32x4 acc[4][2];
#pragma unroll
    for (int mt = 0; mt < 4; ++mt)
#pragma unroll
        for (int nt = 0; nt < 2; ++nt) acc[mt][nt] = f32x4{0.f, 0.f, 0.f, 0.f};

#pragma unroll 1
    for (int dl = 0; dl < 3; ++dl) {
#pragma unroll
        for (int dq = 0; dq < 3; ++dq) {
            const u16* xt = xb + (dl * (P + 2) + dq) * 3200;
            int tap0 = (dl * 3 + dq) * 9;
#pragma unroll
            for (int dwh = 0; dwh < 9; ++dwh) {
                int sd = ((dwh / 3) * 10 + (dwh % 3)) * 32;
                const u16* wp = wb + (tap0 + dwh) * 2048;
                bf16x8 bf[2];
#pragma unroll
                for (int nt = 0; nt < 2; ++nt)
                    bf[nt] = *(const bf16x8*)(wp + nt * 512);
#pragma unroll
                for (int mt = 0; mt < 4; ++mt) {
                    bf16x8 af = *(const bf16x8*)(xt + sp[mt] + sd);
#pragma unroll
                    for (int nt = 0; nt < 2; ++nt)
                        acc[mt][nt] = __builtin_amdgcn_mfma_f32_16x16x32_bf16(
                            af, bf[nt], acc[mt][nt], 0, 0, 0);
                }
            }
        }
    }

    u16* hb = h1pad + HB + b * HSTR + ((l + 1) * (P + 2) + (q + 1)) * 6400;
#pragma unroll
    for (int mt = 0; mt < 4; ++mt)
#pragma unroll
        for (int r = 0; r < 4; ++r) {
            int pos = mt * 16 + quad * 4 + r;
            int w = pos >> 3, h = pos & 7;
            u16* dst = hb + ((w + 1) * 10 + (h + 1)) * 64 + half * 32 + m;
#pragma unroll
            for (int nt = 0; nt < 2; ++nt)
                dst[nt * 16] = f2bf(gelu_exact(acc[mt][nt][r]));
        }
}

__global__ __launch_bounds__(64) void conv1_k(
    const u16* __restrict__ ws_x, const u16* __restrict__ ws_w1,
    u16* __restrict__ ws_h1) {
    int g = blockIdx.x;
    int per = g / 384; int rem = g - per * 384;
    int half = rem / 192; int bt = rem - half * 192;
    if (per == 0)      conv1_body<2>(ws_x, ws_w1, ws_h1, half, bt);
    else if (per == 1) conv1_body<3>(ws_x, ws_w1, ws_h1, half, bt);
    else               conv1_body<4>(ws_x, ws_w1, ws_h1, half, bt);
}

// ---- conv2 (C64->C32). Wave = 32 positions x 32 ch, K=64 (2 Ks). ----
template<int P>
__device__ __forceinline__ void conv2_body(
    const u16* __restrict__ h1pad, const u16* __restrict__ w2b,
    float* __restrict__ orow, int mh, int bt) {
    constexpr int L = 48 / P;
    constexpr int HB = (P == 2) ? HB0 : (P == 3) ? HB1 : HB2;
    constexpr int HSTR = (L + 2) * (P + 2) * 6400;

    int lane = threadIdx.x;
    int m = lane & 15, quad = lane >> 4;
    int b = bt / 48, t = bt - b * 48;
    int l = t / P, q = t - l * P;

    const u16* hbb = h1pad + HB + b * HSTR + (l * (P + 2) + q) * 6400;
    const u16* wb = w2b + m * 64 + quad * 8;

    int sp[2];
#pragma unroll
    for (int mt = 0; mt < 2; ++mt) {
        int pos = mh * 32 + mt * 16 + m;
        sp[mt] = ((pos >> 3) * 10 + (pos & 7)) * 64 + quad * 8;
    }

    f32x4 acc[2][2];
#pragma unroll
    for (int mt = 0; mt < 2; ++mt)
#pragma unroll
        for (int nt = 0; nt < 2; ++nt) acc[mt][nt] = f32x4{0.f, 0.f, 0.f, 0.f};

#pragma unroll 1
    for (int dl = 0; dl < 3; ++dl) {
#pragma unroll
        for (int dq = 0; dq < 3; ++dq) {
            const u16* ht = hbb + (dl * (P + 2) + dq) * 6400;
            int tap0 = (dl * 3 + dq) * 9;
#pragma unroll
            for (int dwh = 0; dwh < 9; ++dwh) {
                int sd = ((dwh / 3) * 10 + (dwh % 3)) * 64;
                const u16* wp = wb + (tap0 + dwh) * 2048;
                bf16x8 bf[2][2];   // [nt][ks]
#pragma unroll
                for (int nt = 0; nt < 2; ++nt)
#pragma unroll
                    for (int ks = 0; ks < 2; ++ks)
                        bf[nt][ks] = *(const bf16x8*)(wp + nt * 1024 + ks * 32);
#pragma unroll
                for (int mt = 0; mt < 2; ++mt)
#pragma unroll
                    for (int ks = 0; ks < 2; ++ks) {
                        bf16x8 af = *(const bf16x8*)(ht + sp[mt] + sd + ks * 32);
#pragma unroll
                        for (int nt = 0; nt < 2; ++nt)
                            acc[mt][nt] = __builtin_amdgcn_mfma_f32_16x16x32_bf16(
                                af, bf[nt][ks], acc[mt][nt], 0, 0, 0);
                    }
            }
        }
    }

#pragma unroll
    for (int mt = 0; mt < 2; ++mt)
#pragma unroll
        for (int nt = 0; nt < 2; ++nt)
#pragma unroll
            for (int r = 0; r < 4; ++r) {
                int pos = mh * 32 + mt * 16 + quad * 4 + r;
                orow[pos * 32 + nt * 16 + m] = acc[mt][nt][r];
            }
}

__global__ __launch_bounds__(64) void conv2_k(
    const u16* __restrict__ ws_h1, const u16* __restrict__ ws_w2,
    float* __restrict__ h2) {
    int g = blockIdx.x;
    int per = g / 384; int rem = g - per * 384;
    int mh = rem / 192; int bt = rem - mh * 192;
    float* orow = h2 + per * H2_PER + bt * 2048;
    if (per == 0)      conv2_body<2>(ws_h1, ws_w2, orow, mh, bt);
    else if (per == 1) conv2_body<3>(ws_h1, ws_w2, orow, mh, bt);
    else               conv2_body<4>(ws_h1, ws_w2, orow, mh, bt);
}

// ---- out = x + (h2_p0 + h2_p1 + h2_p2) / 3 ----
__global__ __launch_bounds__(256) void final_add(
    const float* __restrict__ x, const float* __restrict__ h2,
    float* __restrict__ out) {
    int i = blockIdx.x * 256 + threadIdx.x;
    float4 xv = ((const float4*)x)[i];
    float4 a = ((const float4*)h2)[i];
    float4 bv = ((const float4*)(h2 + H2_PER))[i];
    float4 cv = ((const float4*)(h2 + 2 * H2_PER))[i];
    const float s = 1.0f / 3.0f;
    float4 o;
    o.x = xv.x + (a.x + bv.x + cv.x) * s;
    o.y = xv.y + (a.y + bv.y + cv.y) * s;
    o.z = xv.z + (a.z + bv.z + cv.z) * s;
    o.w = xv.w + (a.w + bv.w + cv.w) * s;
    ((float4*)out)[i] = o;
}

extern "C" void kernel_launch(void* const* d_in, const int* in_sizes, int n_in,
                              void* d_out, int out_size, void* d_ws, size_t ws_size,
                              hipStream_t stream) {
    const float* x    = (const float*)d_in[0];
    const float* w1_0 = (const float*)d_in[1];
    const float* w1_1 = (const float*)d_in[2];
    const float* w2_0 = (const float*)d_in[3];
    const float* w2_1 = (const float*)d_in[4];
    float* out = (float*)d_out;

    u16* ws = (u16*)d_ws;
    u16* ws_x  = ws;            // padded x, 3 layouts
    u16* ws_w1 = ws + W1OFF;
    u16* ws_w2 = ws + W2OFF;
    u16* ws_h1 = ws + H1OFF;    // padded h1, 3 layouts
    float* h2  = (float*)(ws + H2OFF_U16);
    // total ~26.7 MB

    hipMemsetAsync(ws_h1, 0, (size_t)H1TOT * 2, stream);
    prep<<<PREP_N / 256, 256, 0, stream>>>(x, w1_0, w1_1, w2_0, w2_1, ws);
    conv1_k<<<1152, 64, 0, stream>>>(ws_x, ws_w1, ws_h1);
    conv2_k<<<1152, 64, 0, stream>>>(ws_h1, ws_w2, h2);
    final_add<<<H2_PER / 4 / 256, 256, 0, stream>>>(x, h2, out);
}